// Round 2
// baseline (1638.866 us; speedup 1.0000x reference)
//
#include <hip/hip_runtime.h>
#include <math.h>

#define B_ 16
#define S_ 2048
#define D_ 1024
#define SCALE 0.03125f   // 1/sqrt(1024)

typedef __bf16 bf16;
typedef __bf16 bf16x8 __attribute__((ext_vector_type(8)));
typedef float f32x4 __attribute__((ext_vector_type(4)));

#define MFMA(a, b, c) __builtin_amdgcn_mfma_f32_16x16x32_bf16((a), (b), (c), 0, 0, 0)

// ---------------------------------------------------------------------------
// Prep 1: X fp32 -> Y bf16, flat (used for K). 8 elems/thread.
// ---------------------------------------------------------------------------
__global__ __launch_bounds__(256) void cvt_kernel(const float* __restrict__ X,
                                                  bf16* __restrict__ Y) {
  const size_t i = ((size_t)blockIdx.x * 256 + threadIdx.x) * 8;
  float4 a = *(const float4*)(X + i);
  float4 b = *(const float4*)(X + i + 4);
  bf16x8 o;
  o[0] = (bf16)a.x; o[1] = (bf16)a.y; o[2] = (bf16)a.z; o[3] = (bf16)a.w;
  o[4] = (bf16)b.x; o[5] = (bf16)b.y; o[6] = (bf16)b.z; o[7] = (bf16)b.w;
  *(bf16x8*)(Y + i) = o;
}

// ---------------------------------------------------------------------------
// Prep 2: V fp32 [B][S][D] -> VT bf16 [B][D][S] (64x64 tiles via LDS)
// so PV MFMA B-fragments (8 consecutive keys, fixed d) are 16B-contiguous.
// ---------------------------------------------------------------------------
__global__ __launch_bounds__(256) void vt_kernel(const float* __restrict__ V,
                                                 bf16* __restrict__ VT) {
  __shared__ bf16 tile[64][66];  // [s][d], pitch 66 to break bank alignment
  const int b = blockIdx.z;
  const int s0 = blockIdx.x * 64;
  const int d0 = blockIdx.y * 64;
  const float* Vb = V + (size_t)b * S_ * D_;
  bf16* VTb = VT + (size_t)b * D_ * S_;
  const int t = threadIdx.x;
  {
    const int cg = t & 15;   // 16 groups x 4 cols
    const int rr = t >> 4;   // 0..15
#pragma unroll
    for (int p = 0; p < 4; ++p) {
      const int row = rr + 16 * p;
      float4 v = *(const float4*)(Vb + (size_t)(s0 + row) * D_ + d0 + cg * 4);
      tile[row][cg * 4 + 0] = (bf16)v.x;
      tile[row][cg * 4 + 1] = (bf16)v.y;
      tile[row][cg * 4 + 2] = (bf16)v.z;
      tile[row][cg * 4 + 3] = (bf16)v.w;
    }
  }
  __syncthreads();
  {
    const int cg = t & 7;    // 8 groups x 8 s-cols
    const int rr = t >> 3;   // 0..31
#pragma unroll
    for (int p = 0; p < 2; ++p) {
      const int drow = rr + 32 * p;
      bf16x8 o;
#pragma unroll
      for (int i = 0; i < 8; ++i) o[i] = tile[cg * 8 + i][drow];
      *(bf16x8*)(VTb + (size_t)(d0 + drow) * S_ + s0 + cg * 8) = o;
    }
  }
}

// ---------------------------------------------------------------------------
// Flash attention. 512 threads = 8 waves per (batch, 32-row Q tile).
// Wave w owns d-slice [128w, 128w+128): Q A-frags register-resident (converted
// fp32->bf16 once), partial QK^T -> LDS -> cross-wave reduce + online softmax
// (faithful fp32 "*scale - 1e9" collapse) -> P bf16 -> PV from VT, O in AGPRs.
// ---------------------------------------------------------------------------
__global__ __launch_bounds__(512, 2) void attn_kernel(
    const float* __restrict__ Q, const bf16* __restrict__ K,
    const bf16* __restrict__ VT, const int* __restrict__ mask,
    float* __restrict__ out) {
  __shared__ float sc[8][32][68];   // per-wave partial scores (pad 68)
  __shared__ bf16 pbuf[32][72];     // P tile bf16 (pitch 72: 16B-aligned rows)
  __shared__ float madd[32];        // additive mask constant per row (0 or 1e9)
  __shared__ float mS[32], lS[32], alphaS[32];

  const int b = blockIdx.y;
  const int q0 = blockIdx.x * 32;
  const int t = threadIdx.x;
  const int w = t >> 6;          // wave 0..7
  const int lane = t & 63;
  const int n16 = lane & 15;
  const int q4 = lane >> 4;      // quad 0..3
  const int ds0 = w * 128;       // this wave's d-slice

  if (t < 32) {
    madd[t] = mask[b * S_ + q0 + t] ? 0.0f : 1e9f;
    mS[t] = -1e30f;              // finite "-inf": exp(-1e30 - m) == 0
    lS[t] = 0.0f;
  }

  const float* Qb = Q + (size_t)b * S_ * D_;
  const bf16* Kb = K + (size_t)b * S_ * D_;
  const bf16* VTb = VT + (size_t)b * D_ * S_;

  // Q A-fragments (fp32 -> bf16), register resident: qf[mt][kc]
  // lane holds Q[q0 + 16*mt + n16][ds0 + kc*32 + q4*8 + 0..7]
  bf16x8 qf[2][4];
#pragma unroll
  for (int mt = 0; mt < 2; ++mt)
#pragma unroll
    for (int kc = 0; kc < 4; ++kc) {
      const float* qp = Qb + (size_t)(q0 + 16 * mt + n16) * D_ +
                        ds0 + kc * 32 + q4 * 8;
      float4 a = *(const float4*)qp;
      float4 c = *(const float4*)(qp + 4);
      bf16x8 f;
      f[0] = (bf16)a.x; f[1] = (bf16)a.y; f[2] = (bf16)a.z; f[3] = (bf16)a.w;
      f[4] = (bf16)c.x; f[5] = (bf16)c.y; f[6] = (bf16)c.z; f[7] = (bf16)c.w;
      qf[mt][kc] = f;
    }

  // O accumulator: o[mt][nt][r] = O[16*mt + 4*q4 + r][ds0 + nt*16 + n16]
  f32x4 o[2][8];
#pragma unroll
  for (int mt = 0; mt < 2; ++mt)
#pragma unroll
    for (int nt = 0; nt < 8; ++nt) o[mt][nt] = (f32x4){0.f, 0.f, 0.f, 0.f};

  __syncthreads();

  for (int jt = 0; jt < 32; ++jt) {
    const int k0 = jt * 64;

    // ---- phase 1: partial scores S_w[32 x 64] over this wave's 128-d slice
    bf16x8 kf[4][4];  // [nt][kc]: K[k0+nt*16+n16][ds0+kc*32+q4*8+..]
#pragma unroll
    for (int nt = 0; nt < 4; ++nt)
#pragma unroll
      for (int kc = 0; kc < 4; ++kc)
        kf[nt][kc] = *(const bf16x8*)(Kb + (size_t)(k0 + nt * 16 + n16) * D_ +
                                      ds0 + kc * 32 + q4 * 8);
    f32x4 acc[2][4];
#pragma unroll
    for (int mt = 0; mt < 2; ++mt)
#pragma unroll
      for (int nt = 0; nt < 4; ++nt) acc[mt][nt] = (f32x4){0.f, 0.f, 0.f, 0.f};
#pragma unroll
    for (int kc = 0; kc < 4; ++kc)
#pragma unroll
      for (int nt = 0; nt < 4; ++nt)
#pragma unroll
        for (int mt = 0; mt < 2; ++mt)
          acc[mt][nt] = MFMA(qf[mt][kc], kf[nt][kc], acc[mt][nt]);

    // write partials: row = 16*mt + 4*q4 + r, col = nt*16 + n16
#pragma unroll
    for (int mt = 0; mt < 2; ++mt)
#pragma unroll
      for (int nt = 0; nt < 4; ++nt)
#pragma unroll
        for (int r = 0; r < 4; ++r)
          sc[w][16 * mt + 4 * q4 + r][nt * 16 + n16] = acc[mt][nt][r];
    __syncthreads();

    // ---- phase 2: cross-wave reduce + online softmax (32 rows x 16 thr)
    {
      const int r = t >> 4;
      const int cg = t & 15;
      const int c0 = cg * 4;
      float s0v = 0.f, s1v = 0.f, s2v = 0.f, s3v = 0.f;
#pragma unroll
      for (int ww = 0; ww < 8; ++ww) {
        float4 v = *(const float4*)&sc[ww][r][c0];
        s0v += v.x; s1v += v.y; s2v += v.z; s3v += v.w;
      }
      const float ma = madd[r];
      // faithful fp32 order: (dot * scale) then subtract 1e9 -> bit-collapse
      s0v = s0v * SCALE - ma;
      s1v = s1v * SCALE - ma;
      s2v = s2v * SCALE - ma;
      s3v = s3v * SCALE - ma;
      float mx = fmaxf(fmaxf(s0v, s1v), fmaxf(s2v, s3v));
      mx = fmaxf(mx, __shfl_xor(mx, 1));
      mx = fmaxf(mx, __shfl_xor(mx, 2));
      mx = fmaxf(mx, __shfl_xor(mx, 4));
      mx = fmaxf(mx, __shfl_xor(mx, 8));
      const float m_old = mS[r];
      const float m_new = fmaxf(m_old, mx);
      const float p0 = __expf(s0v - m_new);
      const float p1 = __expf(s1v - m_new);
      const float p2 = __expf(s2v - m_new);
      const float p3 = __expf(s3v - m_new);
      float ps = (p0 + p1) + (p2 + p3);
      ps += __shfl_xor(ps, 1);
      ps += __shfl_xor(ps, 2);
      ps += __shfl_xor(ps, 4);
      ps += __shfl_xor(ps, 8);
      if (cg == 0) {
        const float al = __expf(m_old - m_new);  // 0 on first chunk
        alphaS[r] = al;
        lS[r] = lS[r] * al + ps;
        mS[r] = m_new;
      }
      pbuf[r][c0 + 0] = (bf16)p0;
      pbuf[r][c0 + 1] = (bf16)p1;
      pbuf[r][c0 + 2] = (bf16)p2;
      pbuf[r][c0 + 3] = (bf16)p3;
    }
    __syncthreads();

    // ---- phase 3: rescale O by alpha, then O += P @ V_chunk
    f32x4 av[2];
#pragma unroll
    for (int mt = 0; mt < 2; ++mt)
#pragma unroll
      for (int rg = 0; rg < 4; ++rg) av[mt][rg] = alphaS[16 * mt + 4 * q4 + rg];
#pragma unroll
    for (int mt = 0; mt < 2; ++mt)
#pragma unroll
      for (int nt = 0; nt < 8; ++nt) o[mt][nt] *= av[mt];

    bf16x8 pf[2][2];  // P A-frags: P[16*mt + n16][ks*32 + q4*8 + 0..7]
#pragma unroll
    for (int mt = 0; mt < 2; ++mt)
#pragma unroll
      for (int ks = 0; ks < 2; ++ks)
        pf[mt][ks] = *(const bf16x8*)&pbuf[16 * mt + n16][ks * 32 + q4 * 8];

    bf16x8 vf[2][8];  // VT B-frags: VT[ds0 + nt*16 + n16][k0 + ks*32 + q4*8+..]
#pragma unroll
    for (int ks = 0; ks < 2; ++ks)
#pragma unroll
      for (int nt = 0; nt < 8; ++nt)
        vf[ks][nt] = *(const bf16x8*)(VTb + (size_t)(ds0 + nt * 16 + n16) * S_ +
                                      k0 + ks * 32 + q4 * 8);
#pragma unroll
    for (int ks = 0; ks < 2; ++ks)
#pragma unroll
      for (int nt = 0; nt < 8; ++nt)
#pragma unroll
        for (int mt = 0; mt < 2; ++mt)
          o[mt][nt] = MFMA(pf[mt][ks], vf[ks][nt], o[mt][nt]);
  }

  // ---- epilogue: divide by row sums, store fp32
  f32x4 invl[2];
#pragma unroll
  for (int mt = 0; mt < 2; ++mt)
#pragma unroll
    for (int rg = 0; rg < 4; ++rg)
      invl[mt][rg] = 1.0f / lS[16 * mt + 4 * q4 + rg];
#pragma unroll
  for (int mt = 0; mt < 2; ++mt)
#pragma unroll
    for (int nt = 0; nt < 8; ++nt)
#pragma unroll
      for (int rg = 0; rg < 4; ++rg) {
        const size_t row = (size_t)b * S_ + q0 + 16 * mt + 4 * q4 + rg;
        out[row * D_ + ds0 + nt * 16 + n16] = o[mt][nt][rg] * invl[mt][rg];
      }
}

// ---------------------------------------------------------------------------
extern "C" void kernel_launch(void* const* d_in, const int* in_sizes, int n_in,
                              void* d_out, int out_size, void* d_ws, size_t ws_size,
                              hipStream_t stream) {
  (void)in_sizes; (void)n_in; (void)out_size; (void)ws_size;
  const float* Q = (const float*)d_in[0];
  const float* K = (const float*)d_in[1];
  const float* V = (const float*)d_in[2];
  const int* mask = (const int*)d_in[3];
  float* out = (float*)d_out;
  bf16* VT = (bf16*)d_ws;                              // 64 MiB
  bf16* Kb = (bf16*)d_ws + (size_t)B_ * D_ * S_;       // next 64 MiB

  cvt_kernel<<<(B_ * S_ * D_) / (256 * 8), 256, 0, stream>>>(K, Kb);

  dim3 gt(S_ / 64, D_ / 64, B_);
  vt_kernel<<<gt, 256, 0, stream>>>(V, VT);

  dim3 ga(S_ / 32, B_);
  attn_kernel<<<ga, 512, 0, stream>>>(Q, Kb, VT, mask, out);
}

// Round 3
// 1319.676 us; speedup vs baseline: 1.2419x; 1.2419x over previous
//
#include <hip/hip_runtime.h>
#include <math.h>

#define B_ 16
#define S_ 2048
#define D_ 1024
#define SCALE 0.03125f   // 1/sqrt(1024)

typedef __bf16 bf16;
typedef __bf16 bf16x8 __attribute__((ext_vector_type(8)));
typedef float f32x4 __attribute__((ext_vector_type(4)));

#define MFMA(a, b, c) __builtin_amdgcn_mfma_f32_16x16x32_bf16((a), (b), (c), 0, 0, 0)

// ---------------------------------------------------------------------------
// Prep 1: X fp32 -> Y bf16, flat (used for K). 8 elems/thread.
// ---------------------------------------------------------------------------
__global__ __launch_bounds__(256) void cvt_kernel(const float* __restrict__ X,
                                                  bf16* __restrict__ Y) {
  const size_t i = ((size_t)blockIdx.x * 256 + threadIdx.x) * 8;
  float4 a = *(const float4*)(X + i);
  float4 b = *(const float4*)(X + i + 4);
  bf16x8 o;
  o[0] = (bf16)a.x; o[1] = (bf16)a.y; o[2] = (bf16)a.z; o[3] = (bf16)a.w;
  o[4] = (bf16)b.x; o[5] = (bf16)b.y; o[6] = (bf16)b.z; o[7] = (bf16)b.w;
  *(bf16x8*)(Y + i) = o;
}

// ---------------------------------------------------------------------------
// Prep 2: V fp32 [B][S][D] -> VT bf16 [B][D][S] (64x64 tiles via LDS)
// so PV MFMA B-fragments (8 consecutive keys, fixed d) are 16B-contiguous.
// ---------------------------------------------------------------------------
__global__ __launch_bounds__(256) void vt_kernel(const float* __restrict__ V,
                                                 bf16* __restrict__ VT) {
  __shared__ bf16 tile[64][66];  // [s][d], pitch 66 to break bank alignment
  const int b = blockIdx.z;
  const int s0 = blockIdx.x * 64;
  const int d0 = blockIdx.y * 64;
  const float* Vb = V + (size_t)b * S_ * D_;
  bf16* VTb = VT + (size_t)b * D_ * S_;
  const int t = threadIdx.x;
  {
    const int cg = t & 15;   // 16 groups x 4 cols
    const int rr = t >> 4;   // 0..15
#pragma unroll
    for (int p = 0; p < 4; ++p) {
      const int row = rr + 16 * p;
      float4 v = *(const float4*)(Vb + (size_t)(s0 + row) * D_ + d0 + cg * 4);
      tile[row][cg * 4 + 0] = (bf16)v.x;
      tile[row][cg * 4 + 1] = (bf16)v.y;
      tile[row][cg * 4 + 2] = (bf16)v.z;
      tile[row][cg * 4 + 3] = (bf16)v.w;
    }
  }
  __syncthreads();
  {
    const int cg = t & 7;    // 8 groups x 8 s-cols
    const int rr = t >> 3;   // 0..31
#pragma unroll
    for (int p = 0; p < 2; ++p) {
      const int drow = rr + 32 * p;
      bf16x8 o;
#pragma unroll
      for (int i = 0; i < 8; ++i) o[i] = tile[cg * 8 + i][drow];
      *(bf16x8*)(VTb + (size_t)(d0 + drow) * S_ + s0 + cg * 8) = o;
    }
  }
}

// ---------------------------------------------------------------------------
// Flash attention. 512 threads = 8 waves per (batch, 32-row Q tile).
// Wave w owns d-slice [128w, 128w+128): Q A-frags register-resident (converted
// fp32->bf16 once), partial QK^T -> LDS -> cross-wave reduce + online softmax
// (faithful fp32 "*scale - 1e9" collapse) -> P bf16 -> PV from VT, O in regs.
//
// R3: (1) batch->XCD swizzle: 1D grid, b = 2*(d&7)|((d>>3)&1) so XCD x (under
// the blockIdx%8 round-robin heuristic) serves only batches {2x,2x+1} -> K/VT
// j-chunk window stays L2-resident instead of bouncing through LLC.
// (2) vf (VT fragments) issued right after QK MFMAs: latency overlaps
// sc-writes + barrier + softmax instead of being exposed in phase 3.
// ---------------------------------------------------------------------------
__global__ __launch_bounds__(512, 2) void attn_kernel(
    const float* __restrict__ Q, const bf16* __restrict__ K,
    const bf16* __restrict__ VT, const int* __restrict__ mask,
    float* __restrict__ out) {
  __shared__ float sc[8][32][68];   // per-wave partial scores (pad 68)
  __shared__ bf16 pbuf[32][72];     // P tile bf16 (pitch 72: 16B-aligned rows)
  __shared__ float madd[32];        // additive mask constant per row (0 or 1e9)
  __shared__ float mS[32], lS[32], alphaS[32];

  const int d = blockIdx.x;
  const int b = ((d & 7) << 1) | ((d >> 3) & 1);  // batch -> XCD pinning
  const int q0 = (d >> 4) * 32;
  const int t = threadIdx.x;
  const int w = t >> 6;          // wave 0..7
  const int lane = t & 63;
  const int n16 = lane & 15;
  const int q4 = lane >> 4;      // quad 0..3
  const int ds0 = w * 128;       // this wave's d-slice

  if (t < 32) {
    madd[t] = mask[b * S_ + q0 + t] ? 0.0f : 1e9f;
    mS[t] = -1e30f;              // finite "-inf": exp(-1e30 - m) == 0
    lS[t] = 0.0f;
  }

  const float* Qb = Q + (size_t)b * S_ * D_;
  const bf16* Kb = K + (size_t)b * S_ * D_;
  const bf16* VTb = VT + (size_t)b * D_ * S_;

  // Q A-fragments (fp32 -> bf16), register resident: qf[mt][kc]
  // lane holds Q[q0 + 16*mt + n16][ds0 + kc*32 + q4*8 + 0..7]
  bf16x8 qf[2][4];
#pragma unroll
  for (int mt = 0; mt < 2; ++mt)
#pragma unroll
    for (int kc = 0; kc < 4; ++kc) {
      const float* qp = Qb + (size_t)(q0 + 16 * mt + n16) * D_ +
                        ds0 + kc * 32 + q4 * 8;
      float4 a = *(const float4*)qp;
      float4 c = *(const float4*)(qp + 4);
      bf16x8 f;
      f[0] = (bf16)a.x; f[1] = (bf16)a.y; f[2] = (bf16)a.z; f[3] = (bf16)a.w;
      f[4] = (bf16)c.x; f[5] = (bf16)c.y; f[6] = (bf16)c.z; f[7] = (bf16)c.w;
      qf[mt][kc] = f;
    }

  // O accumulator: o[mt][nt][r] = O[16*mt + 4*q4 + r][ds0 + nt*16 + n16]
  f32x4 o[2][8];
#pragma unroll
  for (int mt = 0; mt < 2; ++mt)
#pragma unroll
    for (int nt = 0; nt < 8; ++nt) o[mt][nt] = (f32x4){0.f, 0.f, 0.f, 0.f};

  __syncthreads();

  for (int jt = 0; jt < 32; ++jt) {
    const int k0 = jt * 64;

    // ---- phase 1: partial scores S_w[32 x 64] over this wave's 128-d slice
    bf16x8 kf[4][4];  // [nt][kc]: K[k0+nt*16+n16][ds0+kc*32+q4*8+..]
#pragma unroll
    for (int nt = 0; nt < 4; ++nt)
#pragma unroll
      for (int kc = 0; kc < 4; ++kc)
        kf[nt][kc] = *(const bf16x8*)(Kb + (size_t)(k0 + nt * 16 + n16) * D_ +
                                      ds0 + kc * 32 + q4 * 8);
    f32x4 acc[2][4];
#pragma unroll
    for (int mt = 0; mt < 2; ++mt)
#pragma unroll
      for (int nt = 0; nt < 4; ++nt) acc[mt][nt] = (f32x4){0.f, 0.f, 0.f, 0.f};
#pragma unroll
    for (int kc = 0; kc < 4; ++kc)
#pragma unroll
      for (int nt = 0; nt < 4; ++nt)
#pragma unroll
        for (int mt = 0; mt < 2; ++mt)
          acc[mt][nt] = MFMA(qf[mt][kc], kf[nt][kc], acc[mt][nt]);

    // ---- early-issue VT fragments for phase 3 (independent of softmax);
    // they complete by the barrier drain, so phase 3 starts with data ready.
    bf16x8 vf[2][8];  // [ks][nt]: VT[ds0 + nt*16 + n16][k0 + ks*32 + q4*8+..]
#pragma unroll
    for (int ks = 0; ks < 2; ++ks)
#pragma unroll
      for (int nt = 0; nt < 8; ++nt)
        vf[ks][nt] = *(const bf16x8*)(VTb + (size_t)(ds0 + nt * 16 + n16) * S_ +
                                      k0 + ks * 32 + q4 * 8);

    // write partials: row = 16*mt + 4*q4 + r, col = nt*16 + n16
#pragma unroll
    for (int mt = 0; mt < 2; ++mt)
#pragma unroll
      for (int nt = 0; nt < 4; ++nt)
#pragma unroll
        for (int r = 0; r < 4; ++r)
          sc[w][16 * mt + 4 * q4 + r][nt * 16 + n16] = acc[mt][nt][r];
    __syncthreads();

    // ---- phase 2: cross-wave reduce + online softmax (32 rows x 16 thr)
    {
      const int r = t >> 4;
      const int cg = t & 15;
      const int c0 = cg * 4;
      float s0v = 0.f, s1v = 0.f, s2v = 0.f, s3v = 0.f;
#pragma unroll
      for (int ww = 0; ww < 8; ++ww) {
        float4 v = *(const float4*)&sc[ww][r][c0];
        s0v += v.x; s1v += v.y; s2v += v.z; s3v += v.w;
      }
      const float ma = madd[r];
      // faithful fp32 order: (dot * scale) then subtract 1e9 -> bit-collapse
      s0v = s0v * SCALE - ma;
      s1v = s1v * SCALE - ma;
      s2v = s2v * SCALE - ma;
      s3v = s3v * SCALE - ma;
      float mx = fmaxf(fmaxf(s0v, s1v), fmaxf(s2v, s3v));
      mx = fmaxf(mx, __shfl_xor(mx, 1));
      mx = fmaxf(mx, __shfl_xor(mx, 2));
      mx = fmaxf(mx, __shfl_xor(mx, 4));
      mx = fmaxf(mx, __shfl_xor(mx, 8));
      const float m_old = mS[r];
      const float m_new = fmaxf(m_old, mx);
      const float p0 = __expf(s0v - m_new);
      const float p1 = __expf(s1v - m_new);
      const float p2 = __expf(s2v - m_new);
      const float p3 = __expf(s3v - m_new);
      float ps = (p0 + p1) + (p2 + p3);
      ps += __shfl_xor(ps, 1);
      ps += __shfl_xor(ps, 2);
      ps += __shfl_xor(ps, 4);
      ps += __shfl_xor(ps, 8);
      if (cg == 0) {
        const float al = __expf(m_old - m_new);  // 0 on first chunk
        alphaS[r] = al;
        lS[r] = lS[r] * al + ps;
        mS[r] = m_new;
      }
      pbuf[r][c0 + 0] = (bf16)p0;
      pbuf[r][c0 + 1] = (bf16)p1;
      pbuf[r][c0 + 2] = (bf16)p2;
      pbuf[r][c0 + 3] = (bf16)p3;
    }
    __syncthreads();

    // ---- phase 3: rescale O by alpha, then O += P @ V_chunk
    f32x4 av[2];
#pragma unroll
    for (int mt = 0; mt < 2; ++mt)
#pragma unroll
      for (int rg = 0; rg < 4; ++rg) av[mt][rg] = alphaS[16 * mt + 4 * q4 + rg];
#pragma unroll
    for (int mt = 0; mt < 2; ++mt)
#pragma unroll
      for (int nt = 0; nt < 8; ++nt) o[mt][nt] *= av[mt];

    bf16x8 pf[2][2];  // P A-frags: P[16*mt + n16][ks*32 + q4*8 + 0..7]
#pragma unroll
    for (int mt = 0; mt < 2; ++mt)
#pragma unroll
      for (int ks = 0; ks < 2; ++ks)
        pf[mt][ks] = *(const bf16x8*)&pbuf[16 * mt + n16][ks * 32 + q4 * 8];

#pragma unroll
    for (int ks = 0; ks < 2; ++ks)
#pragma unroll
      for (int nt = 0; nt < 8; ++nt)
#pragma unroll
        for (int mt = 0; mt < 2; ++mt)
          o[mt][nt] = MFMA(pf[mt][ks], vf[ks][nt], o[mt][nt]);
  }

  // ---- epilogue: divide by row sums, store fp32
  f32x4 invl[2];
#pragma unroll
  for (int mt = 0; mt < 2; ++mt)
#pragma unroll
    for (int rg = 0; rg < 4; ++rg)
      invl[mt][rg] = 1.0f / lS[16 * mt + 4 * q4 + rg];
#pragma unroll
  for (int mt = 0; mt < 2; ++mt)
#pragma unroll
    for (int nt = 0; nt < 8; ++nt)
#pragma unroll
      for (int rg = 0; rg < 4; ++rg) {
        const size_t row = (size_t)b * S_ + q0 + 16 * mt + 4 * q4 + rg;
        out[row * D_ + ds0 + nt * 16 + n16] = o[mt][nt][rg] * invl[mt][rg];
      }
}

// ---------------------------------------------------------------------------
extern "C" void kernel_launch(void* const* d_in, const int* in_sizes, int n_in,
                              void* d_out, int out_size, void* d_ws, size_t ws_size,
                              hipStream_t stream) {
  (void)in_sizes; (void)n_in; (void)out_size; (void)ws_size;
  const float* Q = (const float*)d_in[0];
  const float* K = (const float*)d_in[1];
  const float* V = (const float*)d_in[2];
  const int* mask = (const int*)d_in[3];
  float* out = (float*)d_out;
  bf16* VT = (bf16*)d_ws;                              // 64 MiB
  bf16* Kb = (bf16*)d_ws + (size_t)B_ * D_ * S_;       // next 64 MiB

  cvt_kernel<<<(B_ * S_ * D_) / (256 * 8), 256, 0, stream>>>(K, Kb);

  dim3 gt(S_ / 64, D_ / 64, B_);
  vt_kernel<<<gt, 256, 0, stream>>>(V, VT);

  attn_kernel<<<B_ * (S_ / 32), 512, 0, stream>>>(Q, Kb, VT, mask, out);
}